// Round 4
// baseline (156.648 us; speedup 1.0000x reference)
//
#include <hip/hip_runtime.h>

typedef _Float16 half8_t __attribute__((ext_vector_type(8)));
typedef _Float16 half4_t __attribute__((ext_vector_type(4)));
typedef _Float16 half2_t __attribute__((ext_vector_type(2)));
typedef __fp16 fp16x2 __attribute__((ext_vector_type(2)));
typedef float f32x4 __attribute__((ext_vector_type(4)));

#define S_LEN 2048
#define D_DIM 64
#define SD (S_LEN * D_DIM)
#define BC 64
#define NKT (S_LEN / BC)   // 32 key tiles
#define LDK 72             // f16 row stride (64 + 8 pad)
#define LDO 68             // f32 row stride for epilogue
#define THR 4.0f           // lazy-max threshold: stale-path P <= 2^4

// 256 threads = 4 waves; wave w owns q rows [32w,32w+32) as two 16-q groups.
// ROUND-4 STRUCTURE: software-pipelined QK. Rounds 1-3 proved no pipe is
// saturated (VALU 34 / MFMA 27 / LDS ~18 / HBM 6) — the wall is phase
// serialization: softmax(t) depends on QK(t) in-iteration, and barriers
// keep all waves in the same phase, so VALU and MFMA phases never overlap.
// Fix: triple-buffered K/V; barrier sits between stage-writes and reads;
// iteration t computes QK(t+1) [MFMA + ds_read] in the SAME scheduling
// region as softmax(t) [VALU] — independent streams, pipes overlap.
// Kept from prior rounds: P never touches LDS (QK output == PV B-frag for
// 16x16x16f16), lazy running max (no cross-lane in common path), l-sum via
// ones-MFMA, K/V frags shared by both q-groups.
__global__ __launch_bounds__(256, 2)
void fattn_kernel(const float* __restrict__ Qg, const float* __restrict__ Kg,
                  const float* __restrict__ Vg, const int* __restrict__ Mg,
                  float* __restrict__ Og) {
  __shared__ __align__(16) char smem[63488];
  // K bufs: 3 x 9216 at [0,27648); V bufs: 3 x 9216 at [27648,55296)
  float* Msh = (float*)(smem + 55296);  // [2048] additive mask {0,-1e30}
  float* Osh = (float*)smem;            // [128][68] f32, epilogue reuse

  const int t = threadIdx.x;
  const int w = t >> 6;
  const int lane = t & 63;
  const int g = lane >> 4;   // quad
  const int c = lane & 15;

  // bh in low bits: all 16 q-blocks of one (b,h) hit the SAME XCD
  const int bh = blockIdx.x & 31;
  const int qt = blockIdx.x >> 5;
  const int qb = qt * 128;

  const float* Qb = Qg + (size_t)bh * SD;
  const float* Kb = Kg + (size_t)bh * SD;
  const float* Vb = Vg + (size_t)bh * SD;
  const int*   Mb = Mg + (size_t)(bh >> 3) * S_LEN;  // H = 8
  float*       Ob = Og + (size_t)bh * SD;

  // ---- stage additive mask -> LDS once: (m-1)*1e30 -> {0, -1e30} ----
  {
    int4 m0 = *(const int4*)(Mb + 8 * t);
    int4 m1 = *(const int4*)(Mb + 8 * t + 4);
    float4 f0, f1;
    f0.x = (float)(m0.x - 1) * 1e30f; f0.y = (float)(m0.y - 1) * 1e30f;
    f0.z = (float)(m0.z - 1) * 1e30f; f0.w = (float)(m0.w - 1) * 1e30f;
    f1.x = (float)(m1.x - 1) * 1e30f; f1.y = (float)(m1.y - 1) * 1e30f;
    f1.z = (float)(m1.z - 1) * 1e30f; f1.w = (float)(m1.w - 1) * 1e30f;
    *(float4*)(Msh + 8 * t) = f0;
    *(float4*)(Msh + 8 * t + 4) = f1;
  }

  // ---- Q^T B-frags for q = qb + 32w + 16h + c; fold 1/8 * log2(e) ----
  const float qscale = 0.125f * 1.44269504088896340736f;
  half8_t qf[2][2];
#pragma unroll
  for (int h = 0; h < 2; ++h) {
    const float* qp = Qb + (size_t)(qb + 32 * w + 16 * h + c) * D_DIM + 8 * g;
#pragma unroll
    for (int ks = 0; ks < 2; ++ks) {
      float4 lo = *(const float4*)(qp + 32 * ks);
      float4 hi = *(const float4*)(qp + 32 * ks + 4);
      fp16x2 p0 = __builtin_amdgcn_cvt_pkrtz(lo.x * qscale, lo.y * qscale);
      fp16x2 p1 = __builtin_amdgcn_cvt_pkrtz(lo.z * qscale, lo.w * qscale);
      fp16x2 p2 = __builtin_amdgcn_cvt_pkrtz(hi.x * qscale, hi.y * qscale);
      fp16x2 p3 = __builtin_amdgcn_cvt_pkrtz(hi.z * qscale, hi.w * qscale);
      half8_t hh;
      hh[0] = (_Float16)p0[0]; hh[1] = (_Float16)p0[1];
      hh[2] = (_Float16)p1[0]; hh[3] = (_Float16)p1[1];
      hh[4] = (_Float16)p2[0]; hh[5] = (_Float16)p2[1];
      hh[6] = (_Float16)p3[0]; hh[7] = (_Float16)p3[1];
      qf[h][ks] = hh;
    }
  }

  // ---- staging coordinates (256 threads) ----
  const int krow0 = t >> 4;   // 0..15; K row = krow0 + 16*it
  const int kc4   = t & 15;   // K float4 column
  const int vp    = t >> 3;   // V d-pair 0..31
  const int vkpl  = t & 7;    // V key-pair low; kp = vkpl + 8*kc

  float4 kr[4];
  float2 vr[8];
  auto prefetch = [&](int kb2) {
#pragma unroll
    for (int it = 0; it < 4; ++it)
      kr[it] = *(const float4*)(Kb + (size_t)(kb2 + krow0 + 16 * it) * D_DIM + kc4 * 4);
#pragma unroll
    for (int kc = 0; kc < 4; ++kc) {
      const float* vpp = Vb + (size_t)(kb2 + 2 * (vkpl + 8 * kc)) * D_DIM + 2 * vp;
      vr[2 * kc]     = *(const float2*)(vpp);
      vr[2 * kc + 1] = *(const float2*)(vpp + D_DIM);
    }
  };
  auto stage = [&](int buf) {
    _Float16* Kd = (_Float16*)(smem + 9216 * buf);
    _Float16* Vd = (_Float16*)(smem + 27648 + 9216 * buf);
#pragma unroll
    for (int it = 0; it < 4; ++it) {
      fp16x2 a  = __builtin_amdgcn_cvt_pkrtz(kr[it].x, kr[it].y);
      fp16x2 b2 = __builtin_amdgcn_cvt_pkrtz(kr[it].z, kr[it].w);
      half4_t h;
      h[0] = (_Float16)a[0]; h[1] = (_Float16)a[1];
      h[2] = (_Float16)b2[0]; h[3] = (_Float16)b2[1];
      *(half4_t*)(Kd + (krow0 + 16 * it) * LDK + kc4 * 4) = h;
    }
#pragma unroll
    for (int kc = 0; kc < 4; ++kc) {
      int kp = vkpl + 8 * kc;
      fp16x2 h0 = __builtin_amdgcn_cvt_pkrtz(vr[2 * kc].x, vr[2 * kc + 1].x);
      fp16x2 h1 = __builtin_amdgcn_cvt_pkrtz(vr[2 * kc].y, vr[2 * kc + 1].y);
      half2_t g0; g0[0] = (_Float16)h0[0]; g0[1] = (_Float16)h0[1];
      half2_t g1; g1[0] = (_Float16)h1[0]; g1[1] = (_Float16)h1[1];
      *(half2_t*)(Vd + (2 * vp) * LDK + 2 * kp) = g0;
      *(half2_t*)(Vd + (2 * vp + 1) * LDK + 2 * kp) = g1;
    }
  };

  f32x4 acc[2][4];
  f32x4 accl[2];
#pragma unroll
  for (int h = 0; h < 2; ++h) {
#pragma unroll
    for (int j = 0; j < 4; ++j) accl[h][j] = 0.f;
#pragma unroll
    for (int i = 0; i < 4; ++i)
#pragma unroll
      for (int j = 0; j < 4; ++j) acc[h][i][j] = 0.f;
  }
  float mrun[2] = {-1e30f, -1e30f};

  half4_t ones4;
  ones4[0] = (_Float16)1.0f; ones4[1] = (_Float16)1.0f;
  ones4[2] = (_Float16)1.0f; ones4[3] = (_Float16)1.0f;

  // prologue: tile0 -> buf0; tile1 loads in flight; QK(0) computed up front
  prefetch(0);
  stage(0);
  prefetch(BC);
  __syncthreads();

  f32x4 sA[2][4], sB[2][4];
  {
    const _Float16* Kc = (const _Float16*)smem;  // K buf0
#pragma unroll
    for (int mt = 0; mt < 4; ++mt) {
      f32x4 z0, z1;
#pragma unroll
      for (int j = 0; j < 4; ++j) { z0[j] = 0.f; z1[j] = 0.f; }
#pragma unroll
      for (int ks = 0; ks < 2; ++ks) {
        half8_t kf = *(half8_t*)(Kc + (16 * mt + c) * LDK + ks * 32 + 8 * g);
        z0 = __builtin_amdgcn_mfma_f32_16x16x32_f16(kf, qf[0][ks], z0, 0, 0, 0);
        z1 = __builtin_amdgcn_mfma_f32_16x16x32_f16(kf, qf[1][ks], z1, 0, 0, 0);
      }
      sA[0][mt] = z0;
      sA[1][mt] = z1;
    }
  }

  int bV = 0;  // buf holding tile kt (V consumed this iter)
  int bK = 1;  // buf receiving tile kt+1 (K consumed this iter for QK(t+1))

  auto iteration = [&](int kt, f32x4 (&sCur)[2][4], f32x4 (&sNxt)[2][4])
      __attribute__((always_inline)) -> void {
    if (kt <= NKT - 2) stage(bK);                 // tile kt+1 -> buf bK
    if (kt <= NKT - 3) prefetch((kt + 2) * BC);   // refill kr/vr
    __syncthreads();                              // buf bK ready; prior reads done

    const _Float16* Kc = (const _Float16*)(smem + 9216 * bK);
    const _Float16* Vc = (const _Float16*)(smem + 27648 + 9216 * bV);

    // ---- A: QK(t+1) [MFMA+DS] fused with this-tile vf/mask reads.
    //      Independent of B's VALU below -> scheduler overlaps pipes. ----
    f32x4 mvf[4];
    half4_t vf[4][4];  // [d-tile][k-step]
#pragma unroll
    for (int mt = 0; mt < 4; ++mt) {
      if (kt <= NKT - 2) {
        f32x4 z0, z1;
#pragma unroll
        for (int j = 0; j < 4; ++j) { z0[j] = 0.f; z1[j] = 0.f; }
#pragma unroll
        for (int ks = 0; ks < 2; ++ks) {
          half8_t kf = *(half8_t*)(Kc + (16 * mt + c) * LDK + ks * 32 + 8 * g);
          z0 = __builtin_amdgcn_mfma_f32_16x16x32_f16(kf, qf[0][ks], z0, 0, 0, 0);
          z1 = __builtin_amdgcn_mfma_f32_16x16x32_f16(kf, qf[1][ks], z1, 0, 0, 0);
        }
        sNxt[0][mt] = z0;
        sNxt[1][mt] = z1;
      }
      mvf[mt] = *(const f32x4*)(Msh + kt * BC + 16 * mt + 4 * g);
#pragma unroll
      for (int dt = 0; dt < 4; ++dt)
        vf[dt][mt] = *(half4_t*)(Vc + (16 * dt + c) * LDK + 16 * mt + 4 * g);
    }

    // ---- B: mask add + lazy max on CURRENT tile (VALU; overlaps A) ----
#pragma unroll
    for (int h = 0; h < 2; ++h)
#pragma unroll
      for (int mt = 0; mt < 4; ++mt)
#pragma unroll
        for (int r = 0; r < 4; ++r) sCur[h][mt][r] += mvf[mt][r];

    float tl[2];
#pragma unroll
    for (int h = 0; h < 2; ++h) {
      float tm0 = fmaxf(fmaxf(sCur[h][0][0], sCur[h][0][1]),
                        fmaxf(sCur[h][0][2], sCur[h][0][3]));
      float tm1 = fmaxf(fmaxf(sCur[h][1][0], sCur[h][1][1]),
                        fmaxf(sCur[h][1][2], sCur[h][1][3]));
      float tm2 = fmaxf(fmaxf(sCur[h][2][0], sCur[h][2][1]),
                        fmaxf(sCur[h][2][2], sCur[h][2][3]));
      float tm3 = fmaxf(fmaxf(sCur[h][3][0], sCur[h][3][1]),
                        fmaxf(sCur[h][3][2], sCur[h][3][3]));
      tl[h] = fmaxf(fmaxf(tm0, tm1), fmaxf(tm2, tm3));
    }
    int ok0 = __all(tl[0] <= mrun[0] + THR);
    int ok1 = __all(tl[1] <= mrun[1] + THR);
    if (!(ok0 & ok1)) {
      // rare: exact row-max update + alpha rescale (wave-uniform branch)
#pragma unroll
      for (int h = 0; h < 2; ++h) {
        float tmax = tl[h];
        tmax = fmaxf(tmax, __shfl_xor(tmax, 16));
        tmax = fmaxf(tmax, __shfl_xor(tmax, 32));
        float mnew = fmaxf(mrun[h], tmax);
        float alpha = __builtin_amdgcn_exp2f(mrun[h] - mnew);
        mrun[h] = mnew;
        accl[h][0] *= alpha; accl[h][1] *= alpha;
        accl[h][2] *= alpha; accl[h][3] *= alpha;
#pragma unroll
        for (int mt = 0; mt < 4; ++mt) {
          acc[h][mt][0] *= alpha; acc[h][mt][1] *= alpha;
          acc[h][mt][2] *= alpha; acc[h][mt][3] *= alpha;
        }
      }
    }

    // ---- C: exp + in-register pack + PV; l-sum via ones-MFMA.
    //      exp(mt+1) overlaps PV(mt) within the unrolled block. ----
#pragma unroll
    for (int h = 0; h < 2; ++h) {
#pragma unroll
      for (int mt = 0; mt < 4; ++mt) {
        float pv0 = __builtin_amdgcn_exp2f(sCur[h][mt][0] - mrun[h]);
        float pv1 = __builtin_amdgcn_exp2f(sCur[h][mt][1] - mrun[h]);
        float pv2 = __builtin_amdgcn_exp2f(sCur[h][mt][2] - mrun[h]);
        float pv3 = __builtin_amdgcn_exp2f(sCur[h][mt][3] - mrun[h]);
        fp16x2 p01 = __builtin_amdgcn_cvt_pkrtz(pv0, pv1);
        fp16x2 p23 = __builtin_amdgcn_cvt_pkrtz(pv2, pv3);
        half4_t pf;
        pf[0] = (_Float16)p01[0]; pf[1] = (_Float16)p01[1];
        pf[2] = (_Float16)p23[0]; pf[3] = (_Float16)p23[1];
        accl[h] = __builtin_amdgcn_mfma_f32_16x16x16f16(ones4, pf, accl[h], 0, 0, 0);
#pragma unroll
        for (int dt = 0; dt < 4; ++dt)
          acc[h][dt] = __builtin_amdgcn_mfma_f32_16x16x16f16(vf[dt][mt], pf,
                                                             acc[h][dt], 0, 0, 0);
      }
    }

    // rotate triple buffers
    bV = bK;
    bK = (bK == 2) ? 0 : bK + 1;
  };

  for (int tt = 0; tt < NKT; tt += 2) {
    iteration(tt, sA, sB);      // static double-buffer of scores (rule #20)
    iteration(tt + 1, sB, sA);
  }

  // ---- epilogue: /l, transpose O^T -> O via LDS, coalesced stores ----
#pragma unroll
  for (int h = 0; h < 2; ++h) {
    float linv = 1.f / accl[h][0];  // ones-MFMA replicates l over rows
#pragma unroll
    for (int mt = 0; mt < 4; ++mt)
#pragma unroll
      for (int r = 0; r < 4; ++r)
        Osh[(32 * w + 16 * h + c) * LDO + 16 * mt + 4 * g + r] = acc[h][mt][r] * linv;
  }
  __syncthreads();
  {
    int f8 = t & 7;
#pragma unroll
    for (int i = 0; i < 4; ++i) {
      int q = (t >> 3) + 32 * i;
#pragma unroll
      for (int j = 0; j < 2; ++j) {
        int c4 = f8 + 8 * j;
        f32x4 o = *(f32x4*)(Osh + q * LDO + c4 * 4);
        *(float4*)(Ob + (size_t)(qb + q) * D_DIM + c4 * 4) =
            make_float4(o.x, o.y, o.z, o.w);
      }
    }
  }
}

extern "C" void kernel_launch(void* const* d_in, const int* in_sizes, int n_in,
                              void* d_out, int out_size, void* d_ws, size_t ws_size,
                              hipStream_t stream) {
  (void)in_sizes; (void)n_in; (void)d_ws; (void)ws_size; (void)out_size;
  const float* Q = (const float*)d_in[0];
  const float* K = (const float*)d_in[1];
  const float* V = (const float*)d_in[2];
  const int*   M = (const int*)d_in[3];
  float* O = (float*)d_out;
  // grid: bh fast (XCD locality), 16 q-tiles slow
  fattn_kernel<<<dim3(32 * 16), dim3(256), 0, stream>>>(Q, K, V, M, O);
}

// Round 5
// 141.858 us; speedup vs baseline: 1.1043x; 1.1043x over previous
//
#include <hip/hip_runtime.h>

typedef _Float16 half8_t __attribute__((ext_vector_type(8)));
typedef _Float16 half4_t __attribute__((ext_vector_type(4)));
typedef _Float16 half2_t __attribute__((ext_vector_type(2)));
typedef __fp16 fp16x2 __attribute__((ext_vector_type(2)));
typedef float f32x4 __attribute__((ext_vector_type(4)));

#define S_LEN 2048
#define D_DIM 64
#define SD (S_LEN * D_DIM)
#define BC 64
#define NKT (S_LEN / BC)   // 32 key tiles
#define LDK 72             // fallback kernel: f16 row stride (64 + 8 pad)
#define LDO 68             // f32 row stride for epilogue
#define THR 4.0f           // lazy-max threshold: stale-path P <= 2^4
#define WS_NEED ((size_t)16 * 1024 * 1024)

// ============================================================================
// PREP: K -> f16 tiles, V -> transposed f16 tiles, laid out in d_ws in the
// EXACT byte order the main kernel's LDS wants (XOR bank-swizzle baked in).
// K tile (8KB): byte(row,16B-granule j) = row*128 + ((16j) ^ ((row&7)<<4)),
//   granule j holds K[row][8j..8j+8).  (row = key within tile)
// V tile (8KB): byte(drow,8B-granule j2) = drow*128 + ((8j2) ^ ((drow&15)<<3)),
//   granule j2 holds V^T[drow][4j2..4j2+4) = V[4j2..][drow].
// Rationale: all 16 q-tile blocks of one bh previously re-did this conversion
// + staging (16x redundant VALU/LDS work); now it's done once and the main
// kernel stages via pure global_load_lds DMA.
// ============================================================================
__global__ __launch_bounds__(256)
void prep_kernel(const float* __restrict__ Kg, const float* __restrict__ Vg,
                 _Float16* __restrict__ wsK, _Float16* __restrict__ wsV) {
  __shared__ float vt[64][68];
  const int blk = blockIdx.x;   // [0,1024): K tiles; [1024,2048): V tiles
  const int t = threadIdx.x;

  if (blk < 1024) {
    const int bh = blk >> 5, kt = blk & 31;
    const float* src = Kg + (size_t)bh * SD + (size_t)kt * BC * D_DIM;
    char* dst = (char*)wsK + (size_t)blk * 8192;
#pragma unroll
    for (int i = 0; i < 2; ++i) {
      int task = t + 256 * i;        // 512 granules: row 0..63 x j 0..7
      int row = task >> 3, j = task & 7;
      float4 lo = *(const float4*)(src + row * D_DIM + 8 * j);
      float4 hi = *(const float4*)(src + row * D_DIM + 8 * j + 4);
      fp16x2 p0 = __builtin_amdgcn_cvt_pkrtz(lo.x, lo.y);
      fp16x2 p1 = __builtin_amdgcn_cvt_pkrtz(lo.z, lo.w);
      fp16x2 p2 = __builtin_amdgcn_cvt_pkrtz(hi.x, hi.y);
      fp16x2 p3 = __builtin_amdgcn_cvt_pkrtz(hi.z, hi.w);
      half8_t h;
      h[0] = (_Float16)p0[0]; h[1] = (_Float16)p0[1];
      h[2] = (_Float16)p1[0]; h[3] = (_Float16)p1[1];
      h[4] = (_Float16)p2[0]; h[5] = (_Float16)p2[1];
      h[6] = (_Float16)p3[0]; h[7] = (_Float16)p3[1];
      *(half8_t*)(dst + row * 128 + ((16 * j) ^ ((row & 7) << 4))) = h;
    }
  } else {
    const int vb = blk - 1024;
    const int bh = vb >> 5, kt = vb & 31;
    const float* src = Vg + (size_t)bh * SD + (size_t)kt * BC * D_DIM;
    // coalesced load of the 64x64 f32 V tile
#pragma unroll
    for (int i = 0; i < 4; ++i) {
      int r = (t >> 4) + 16 * i, c4 = t & 15;
      *(float4*)&vt[r][c4 * 4] = *(const float4*)(src + r * D_DIM + c4 * 4);
    }
    __syncthreads();
    char* dst = (char*)wsV + (size_t)vb * 8192;
#pragma unroll
    for (int i = 0; i < 4; ++i) {
      int task = t + 256 * i;        // 1024 granules: drow 0..63 x j2 0..15
      int drow = task >> 4, j2 = task & 15, k0 = 4 * j2;
      float a = vt[k0][drow], b = vt[k0 + 1][drow];
      float cc = vt[k0 + 2][drow], d = vt[k0 + 3][drow];
      fp16x2 h0 = __builtin_amdgcn_cvt_pkrtz(a, b);
      fp16x2 h1 = __builtin_amdgcn_cvt_pkrtz(cc, d);
      half4_t h;
      h[0] = (_Float16)h0[0]; h[1] = (_Float16)h0[1];
      h[2] = (_Float16)h1[0]; h[3] = (_Float16)h1[1];
      *(half4_t*)(dst + drow * 128 + ((8 * j2) ^ ((drow & 15) << 3))) = h;
    }
  }
}

// ============================================================================
// MAIN: round-3 compute body (lazy max, ones-MFMA l-sum, in-register P->PV,
// K/V frags shared by 2 q-groups), with staging replaced by pure DMA:
// 4 global_load_lds(16B) per wave per iter from the pre-converted, pre-swizzled
// f16 workspace. Zero staging VALU, zero ds_writes, zero prefetch registers.
// ============================================================================
__global__ __launch_bounds__(256, 2)
void fattn_dma(const float* __restrict__ Qg, const _Float16* __restrict__ wsK,
               const _Float16* __restrict__ wsV, const int* __restrict__ Mg,
               float* __restrict__ Og) {
  __shared__ __align__(16) char smem[40960];
  // K dbuf 2x8192 [0,16384); V dbuf 2x8192 [16384,32768); mask [32768,40960)
  float* Msh = (float*)(smem + 32768);
  float* Osh = (float*)smem;   // epilogue reuse (34816B, mask dead by then)

  const int t = threadIdx.x;
  const int w = t >> 6;
  const int lane = t & 63;
  const int g = lane >> 4;
  const int c = lane & 15;

  const int bh = blockIdx.x & 31;
  const int qt = blockIdx.x >> 5;
  const int qb = qt * 128;

  const float* Qb = Qg + (size_t)bh * SD;
  const int*   Mb = Mg + (size_t)(bh >> 3) * S_LEN;  // H = 8
  float*       Ob = Og + (size_t)bh * SD;

  // ---- stage additive mask -> LDS once ----
  {
    int4 m0 = *(const int4*)(Mb + 8 * t);
    int4 m1 = *(const int4*)(Mb + 8 * t + 4);
    float4 f0, f1;
    f0.x = (float)(m0.x - 1) * 1e30f; f0.y = (float)(m0.y - 1) * 1e30f;
    f0.z = (float)(m0.z - 1) * 1e30f; f0.w = (float)(m0.w - 1) * 1e30f;
    f1.x = (float)(m1.x - 1) * 1e30f; f1.y = (float)(m1.y - 1) * 1e30f;
    f1.z = (float)(m1.z - 1) * 1e30f; f1.w = (float)(m1.w - 1) * 1e30f;
    *(float4*)(Msh + 8 * t) = f0;
    *(float4*)(Msh + 8 * t + 4) = f1;
  }

  // ---- Q^T B-frags; fold 1/8 * log2(e) ----
  const float qscale = 0.125f * 1.44269504088896340736f;
  half8_t qf[2][2];
#pragma unroll
  for (int h = 0; h < 2; ++h) {
    const float* qp = Qb + (size_t)(qb + 32 * w + 16 * h + c) * D_DIM + 8 * g;
#pragma unroll
    for (int ks = 0; ks < 2; ++ks) {
      float4 lo = *(const float4*)(qp + 32 * ks);
      float4 hi = *(const float4*)(qp + 32 * ks + 4);
      fp16x2 p0 = __builtin_amdgcn_cvt_pkrtz(lo.x * qscale, lo.y * qscale);
      fp16x2 p1 = __builtin_amdgcn_cvt_pkrtz(lo.z * qscale, lo.w * qscale);
      fp16x2 p2 = __builtin_amdgcn_cvt_pkrtz(hi.x * qscale, hi.y * qscale);
      fp16x2 p3 = __builtin_amdgcn_cvt_pkrtz(hi.z * qscale, hi.w * qscale);
      half8_t hh;
      hh[0] = (_Float16)p0[0]; hh[1] = (_Float16)p0[1];
      hh[2] = (_Float16)p1[0]; hh[3] = (_Float16)p1[1];
      hh[4] = (_Float16)p2[0]; hh[5] = (_Float16)p2[1];
      hh[6] = (_Float16)p3[0]; hh[7] = (_Float16)p3[1];
      qf[h][ks] = hh;
    }
  }

  // ---- DMA staging: per wave, 2KB of K + 2KB of V (4 x 16B/lane issues) ----
  const size_t tile_base0 = (size_t)bh * 32 * 8192;
  auto dma = [&](int buf, int kt) {
    const char* gK = (const char*)wsK + tile_base0 + (size_t)kt * 8192 +
                     w * 2048 + lane * 16;
    const char* gV = (const char*)wsV + tile_base0 + (size_t)kt * 8192 +
                     w * 2048 + lane * 16;
    char* lK = smem + 8192 * buf + w * 2048;
    char* lV = smem + 16384 + 8192 * buf + w * 2048;
    __builtin_amdgcn_global_load_lds((const float*)gK, (float*)lK, 16, 0, 0);
    __builtin_amdgcn_global_load_lds((const float*)(gK + 1024), (float*)(lK + 1024), 16, 0, 0);
    __builtin_amdgcn_global_load_lds((const float*)gV, (float*)lV, 16, 0, 0);
    __builtin_amdgcn_global_load_lds((const float*)(gV + 1024), (float*)(lV + 1024), 16, 0, 0);
  };

  f32x4 acc[2][4];
  f32x4 accl[2];
#pragma unroll
  for (int h = 0; h < 2; ++h) {
#pragma unroll
    for (int j = 0; j < 4; ++j) accl[h][j] = 0.f;
#pragma unroll
    for (int i = 0; i < 4; ++i)
#pragma unroll
      for (int j = 0; j < 4; ++j) acc[h][i][j] = 0.f;
  }
  float mrun[2] = {-1e30f, -1e30f};

  half4_t ones4;
  ones4[0] = (_Float16)1.0f; ones4[1] = (_Float16)1.0f;
  ones4[2] = (_Float16)1.0f; ones4[3] = (_Float16)1.0f;

  // loop-invariant swizzled frag byte-offsets (per lane)
  const int kxor = (c & 7) << 4;
  const int vxor = c << 3;

  dma(0, 0);
  __syncthreads();   // drains vmcnt: tile 0 resident

  for (int kt = 0; kt < NKT; ++kt) {
    const int cur = kt & 1;
    if (kt < NKT - 1) dma(cur ^ 1, kt + 1);   // in flight under compute

    const char* Kc = smem + 8192 * cur;
    const char* Vc = smem + 16384 + 8192 * cur;

    // ---- S^T = K . Q^T for both q-groups; K frag read ONCE ----
    f32x4 sT[2][4];
    __builtin_amdgcn_s_setprio(1);
#pragma unroll
    for (int mt = 0; mt < 4; ++mt) {
      f32x4 z0, z1;
#pragma unroll
      for (int j = 0; j < 4; ++j) { z0[j] = 0.f; z1[j] = 0.f; }
#pragma unroll
      for (int ks = 0; ks < 2; ++ks) {
        half8_t kf = *(const half8_t*)(Kc + (16 * mt + c) * 128 +
                                       ((ks * 64 + g * 16) ^ kxor));
        z0 = __builtin_amdgcn_mfma_f32_16x16x32_f16(kf, qf[0][ks], z0, 0, 0, 0);
        z1 = __builtin_amdgcn_mfma_f32_16x16x32_f16(kf, qf[1][ks], z1, 0, 0, 0);
      }
      sT[0][mt] = z0;
      sT[1][mt] = z1;
    }
    __builtin_amdgcn_s_setprio(0);

    // ---- V A-frags (K=16 PV), shared by both groups ----
    half4_t vf[4][4];  // [d-tile][k-step]
#pragma unroll
    for (int dt = 0; dt < 4; ++dt)
#pragma unroll
      for (int mtk = 0; mtk < 4; ++mtk)
        vf[dt][mtk] = *(const half4_t*)(Vc + (16 * dt + c) * 128 +
                                        ((mtk * 32 + g * 8) ^ vxor));

    // ---- additive mask ----
    f32x4 mvf[4];
#pragma unroll
    for (int mt = 0; mt < 4; ++mt)
      mvf[mt] = *(const f32x4*)(Msh + kt * BC + 16 * mt + 4 * g);
#pragma unroll
    for (int h = 0; h < 2; ++h)
#pragma unroll
      for (int mt = 0; mt < 4; ++mt)
#pragma unroll
        for (int r = 0; r < 4; ++r) sT[h][mt][r] += mvf[mt][r];

    // ---- lazy max: per-lane local max only in the common path ----
    float tl[2];
#pragma unroll
    for (int h = 0; h < 2; ++h) {
      float tm0 = fmaxf(fmaxf(sT[h][0][0], sT[h][0][1]),
                        fmaxf(sT[h][0][2], sT[h][0][3]));
      float tm1 = fmaxf(fmaxf(sT[h][1][0], sT[h][1][1]),
                        fmaxf(sT[h][1][2], sT[h][1][3]));
      float tm2 = fmaxf(fmaxf(sT[h][2][0], sT[h][2][1]),
                        fmaxf(sT[h][2][2], sT[h][2][3]));
      float tm3 = fmaxf(fmaxf(sT[h][3][0], sT[h][3][1]),
                        fmaxf(sT[h][3][2], sT[h][3][3]));
      tl[h] = fmaxf(fmaxf(tm0, tm1), fmaxf(tm2, tm3));
    }
    int ok0 = __all(tl[0] <= mrun[0] + THR);
    int ok1 = __all(tl[1] <= mrun[1] + THR);
    if (!(ok0 & ok1)) {
#pragma unroll
      for (int h = 0; h < 2; ++h) {
        float tmax = tl[h];
        tmax = fmaxf(tmax, __shfl_xor(tmax, 16));
        tmax = fmaxf(tmax, __shfl_xor(tmax, 32));
        float mnew = fmaxf(mrun[h], tmax);
        float alpha = __builtin_amdgcn_exp2f(mrun[h] - mnew);
        mrun[h] = mnew;
        accl[h][0] *= alpha; accl[h][1] *= alpha;
        accl[h][2] *= alpha; accl[h][3] *= alpha;
#pragma unroll
        for (int mt = 0; mt < 4; ++mt) {
          acc[h][mt][0] *= alpha; acc[h][mt][1] *= alpha;
          acc[h][mt][2] *= alpha; acc[h][mt][3] *= alpha;
        }
      }
    }

    // ---- exp + in-register pack + PV; l-sum via ones-MFMA ----
    __builtin_amdgcn_s_setprio(1);
#pragma unroll
    for (int h = 0; h < 2; ++h) {
#pragma unroll
      for (int mt = 0; mt < 4; ++mt) {
        float pv0 = __builtin_amdgcn_exp2f(sT[h][mt][0] - mrun[h]);
        float pv1 = __builtin_amdgcn_exp2f(sT[h][mt][1] - mrun[h]);
        float pv2 = __builtin_amdgcn_exp2f(sT[h][mt][2] - mrun[h]);
        float pv3 = __builtin_amdgcn_exp2f(sT[h][mt][3] - mrun[h]);
        fp16x2 p01 = __builtin_amdgcn_cvt_pkrtz(pv0, pv1);
        fp16x2 p23 = __builtin_amdgcn_cvt_pkrtz(pv2, pv3);
        half4_t pf;
        pf[0] = (_Float16)p01[0]; pf[1] = (_Float16)p01[1];
        pf[2] = (_Float16)p23[0]; pf[3] = (_Float16)p23[1];
        accl[h] = __builtin_amdgcn_mfma_f32_16x16x16f16(ones4, pf, accl[h], 0, 0, 0);
#pragma unroll
        for (int dt = 0; dt < 4; ++dt)
          acc[h][dt] = __builtin_amdgcn_mfma_f32_16x16x16f16(vf[dt][mt], pf,
                                                             acc[h][dt], 0, 0, 0);
      }
    }
    __builtin_amdgcn_s_setprio(0);

    __syncthreads();  // drains vmcnt (DMA kt+1 done) + lgkm; guards swap
  }

  // ---- epilogue: /l, transpose O^T -> O via LDS, coalesced stores ----
#pragma unroll
  for (int h = 0; h < 2; ++h) {
    float linv = 1.f / accl[h][0];
#pragma unroll
    for (int mt = 0; mt < 4; ++mt)
#pragma unroll
      for (int r = 0; r < 4; ++r)
        Osh[(32 * w + 16 * h + c) * LDO + 16 * mt + 4 * g + r] = acc[h][mt][r] * linv;
  }
  __syncthreads();
  {
    int f8 = t & 7;
#pragma unroll
    for (int i = 0; i < 4; ++i) {
      int q = (t >> 3) + 32 * i;
#pragma unroll
      for (int j = 0; j < 2; ++j) {
        int c4 = f8 + 8 * j;
        f32x4 o = *(f32x4*)(Osh + q * LDO + c4 * 4);
        *(float4*)(Ob + (size_t)(qb + q) * D_DIM + c4 * 4) =
            make_float4(o.x, o.y, o.z, o.w);
      }
    }
  }
}

// ============================================================================
// FALLBACK (round-3 kernel, 87us) — used only if ws_size < 16MB.
// ============================================================================
__global__ __launch_bounds__(256, 2)
void fattn_fb(const float* __restrict__ Qg, const float* __restrict__ Kg,
              const float* __restrict__ Vg, const int* __restrict__ Mg,
              float* __restrict__ Og) {
  __shared__ __align__(16) char smem[45056];
  float* Msh = (float*)(smem + 36864);
  float* Osh = (float*)smem;

  const int t = threadIdx.x;
  const int w = t >> 6;
  const int lane = t & 63;
  const int g = lane >> 4;
  const int c = lane & 15;

  const int bh = blockIdx.x & 31;
  const int qt = blockIdx.x >> 5;
  const int qb = qt * 128;

  const float* Qb = Qg + (size_t)bh * SD;
  const float* Kb = Kg + (size_t)bh * SD;
  const float* Vb = Vg + (size_t)bh * SD;
  const int*   Mb = Mg + (size_t)(bh >> 3) * S_LEN;
  float*       Ob = Og + (size_t)bh * SD;

  {
    int4 m0 = *(const int4*)(Mb + 8 * t);
    int4 m1 = *(const int4*)(Mb + 8 * t + 4);
    float4 f0, f1;
    f0.x = (float)(m0.x - 1) * 1e30f; f0.y = (float)(m0.y - 1) * 1e30f;
    f0.z = (float)(m0.z - 1) * 1e30f; f0.w = (float)(m0.w - 1) * 1e30f;
    f1.x = (float)(m1.x - 1) * 1e30f; f1.y = (float)(m1.y - 1) * 1e30f;
    f1.z = (float)(m1.z - 1) * 1e30f; f1.w = (float)(m1.w - 1) * 1e30f;
    *(float4*)(Msh + 8 * t) = f0;
    *(float4*)(Msh + 8 * t + 4) = f1;
  }

  const float qscale = 0.125f * 1.44269504088896340736f;
  half8_t qf[2][2];
#pragma unroll
  for (int h = 0; h < 2; ++h) {
    const float* qp = Qb + (size_t)(qb + 32 * w + 16 * h + c) * D_DIM + 8 * g;
#pragma unroll
    for (int ks = 0; ks < 2; ++ks) {
      float4 lo = *(const float4*)(qp + 32 * ks);
      float4 hi = *(const float4*)(qp + 32 * ks + 4);
      fp16x2 p0 = __builtin_amdgcn_cvt_pkrtz(lo.x * qscale, lo.y * qscale);
      fp16x2 p1 = __builtin_amdgcn_cvt_pkrtz(lo.z * qscale, lo.w * qscale);
      fp16x2 p2 = __builtin_amdgcn_cvt_pkrtz(hi.x * qscale, hi.y * qscale);
      fp16x2 p3 = __builtin_amdgcn_cvt_pkrtz(hi.z * qscale, hi.w * qscale);
      half8_t hh;
      hh[0] = (_Float16)p0[0]; hh[1] = (_Float16)p0[1];
      hh[2] = (_Float16)p1[0]; hh[3] = (_Float16)p1[1];
      hh[4] = (_Float16)p2[0]; hh[5] = (_Float16)p2[1];
      hh[6] = (_Float16)p3[0]; hh[7] = (_Float16)p3[1];
      qf[h][ks] = hh;
    }
  }

  const int krow0 = t >> 4;
  const int kc4   = t & 15;
  const int vp    = t >> 3;
  const int vkpl  = t & 7;

  float4 kr[4];
  float2 vr[8];
  auto prefetch = [&](int kb2) {
#pragma unroll
    for (int it = 0; it < 4; ++it)
      kr[it] = *(const float4*)(Kb + (size_t)(kb2 + krow0 + 16 * it) * D_DIM + kc4 * 4);
#pragma unroll
    for (int kc = 0; kc < 4; ++kc) {
      const float* vpp = Vb + (size_t)(kb2 + 2 * (vkpl + 8 * kc)) * D_DIM + 2 * vp;
      vr[2 * kc]     = *(const float2*)(vpp);
      vr[2 * kc + 1] = *(const float2*)(vpp + D_DIM);
    }
  };
  auto stage = [&](int buf) {
    _Float16* Kd = (_Float16*)(smem + 9216 * buf);
    _Float16* Vd = (_Float16*)(smem + 18432 + 9216 * buf);
#pragma unroll
    for (int it = 0; it < 4; ++it) {
      fp16x2 a  = __builtin_amdgcn_cvt_pkrtz(kr[it].x, kr[it].y);
      fp16x2 b2 = __builtin_amdgcn_cvt_pkrtz(kr[it].z, kr[it].w);
      half4_t h;
      h[0] = (_Float16)a[0]; h[1] = (_Float16)a[1];
      h[2] = (_Float16)b2[0]; h[3] = (_Float16)b2[1];
      *(half4_t*)(Kd + (krow0 + 16 * it) * LDK + kc4 * 4) = h;
    }
#pragma unroll
    for (int kc = 0; kc < 4; ++kc) {
      int kp = vkpl + 8 * kc;
      fp16x2 h0 = __builtin_amdgcn_cvt_pkrtz(vr[2 * kc].x, vr[2 * kc + 1].x);
      fp16x2 h1 = __builtin_amdgcn_cvt_pkrtz(vr[2 * kc].y, vr[2 * kc + 1].y);
      half2_t g0; g0[0] = (_Float16)h0[0]; g0[1] = (_Float16)h0[1];
      half2_t g1; g1[0] = (_Float16)h1[0]; g1[1] = (_Float16)h1[1];
      *(half2_t*)(Vd + (2 * vp) * LDK + 2 * kp) = g0;
      *(half2_t*)(Vd + (2 * vp + 1) * LDK + 2 * kp) = g1;
    }
  };

  f32x4 acc[2][4];
  f32x4 accl[2];
#pragma unroll
  for (int h = 0; h < 2; ++h) {
#pragma unroll
    for (int j = 0; j < 4; ++j) accl[h][j] = 0.f;
#pragma unroll
    for (int i = 0; i < 4; ++i)
#pragma unroll
      for (int j = 0; j < 4; ++j) acc[h][i][j] = 0.f;
  }
  float mrun[2] = {-1e30f, -1e30f};

  half4_t ones4;
  ones4[0] = (_Float16)1.0f; ones4[1] = (_Float16)1.0f;
  ones4[2] = (_Float16)1.0f; ones4[3] = (_Float16)1.0f;

  prefetch(0);
  stage(0);
  prefetch(BC);
  __syncthreads();

  for (int kt = 0; kt < NKT; ++kt) {
    const int kb = kt * BC;
    const int cur = kt & 1;

    if (kt < NKT - 1) stage(cur ^ 1);
    if (kt < NKT - 2) prefetch(kb + 2 * BC);

    const _Float16* Kc = (const _Float16*)(smem + 9216 * cur);
    const _Float16* Vc = (const _Float16*)(smem + 18432 + 9216 * cur);

    f32x4 sT[2][4];
    __builtin_amdgcn_s_setprio(1);
#pragma unroll
    for (int mt = 0; mt < 4; ++mt) {
      f32x4 z0, z1;
#pragma unroll
      for (int j = 0; j < 4; ++j) { z0[j] = 0.f; z1[j] = 0.f; }
#pragma unroll
      for (int ks = 0; ks < 2; ++ks) {
        half8_t kf = *(half8_t*)(Kc + (16 * mt + c) * LDK + ks * 32 + 8 * g);
        z0 = __builtin_amdgcn_mfma_f32_16x16x32_f16(kf, qf[0][ks], z0, 0, 0, 0);
        z1 = __builtin_amdgcn_mfma_f32_16x16x32_f16(kf, qf[1][ks], z1, 0, 0, 0);
      }
      sT[0][mt] = z0;
      sT[1][mt] = z1;
    }
    __builtin_amdgcn_s_setprio(0);

    half4_t vf[4][4];
#pragma unroll
    for (int dt = 0; dt < 4; ++dt)
#pragma unroll
      for (int kst = 0; kst < 4; ++kst)
        vf[dt][kst] = *(half4_t*)(Vc + (16 * dt + c) * LDK + 16 * kst + 4 * g);

    f32x4 mvf[4];
#pragma unroll
    for (int mt = 0; mt < 4; ++mt)
      mvf[mt] = *(const f32x4*)(Msh + kb + 16 * mt + 4 * g);
#pragma unroll
    for (int h = 0; h < 2; ++h)
#pragma unroll
      for (int mt = 0; mt < 4; ++mt)
#pragma unroll
        for (int r = 0; r < 4; ++r) sT[h][mt][r] += mvf[mt][r];

    float tl[2];
#pragma unroll
    for (int h = 0; h < 2; ++h) {
      float tm0 = fmaxf(fmaxf(sT[h][0][0], sT[h][0][1]),
                        fmaxf(sT[h][0][2], sT[h][0][3]));
      float tm1 = fmaxf(fmaxf(sT[h][1][0], sT[h][1][1]),
                        fmaxf(sT[h][1][2], sT[h][1][3]));
      float tm2 = fmaxf(fmaxf(sT[h][2][0], sT[h][2][1]),
                        fmaxf(sT[h][2][2], sT[h][2][3]));
      float tm3 = fmaxf(fmaxf(sT[h][3][0], sT[h][3][1]),
                        fmaxf(sT[h][3][2], sT[h][3][3]));
      tl[h] = fmaxf(fmaxf(tm0, tm1), fmaxf(tm2, tm3));
    }
    int ok0 = __all(tl[0] <= mrun[0] + THR);
    int ok1 = __all(tl[1] <= mrun[1] + THR);
    if (!(ok0 & ok1)) {
#pragma unroll
      for (int h = 0; h < 2; ++h) {
        float tmax = tl[h];
        tmax = fmaxf(tmax, __shfl_xor(tmax, 16));
        tmax = fmaxf(tmax, __shfl_xor(tmax, 32));
        float mnew = fmaxf(mrun[h], tmax);
        float alpha = __builtin_amdgcn_exp2f(mrun[h] - mnew);
        mrun[h] = mnew;
        accl[h][0] *= alpha; accl[h][1] *= alpha;
        accl[h][2] *= alpha; accl[h][3] *= alpha;
#pragma unroll
        for (int mt = 0; mt < 4; ++mt) {
          acc[h][mt][0] *= alpha; acc[h][mt][1] *= alpha;
          acc[h][mt][2] *= alpha; acc[h][mt][3] *= alpha;
        }
      }
    }

    __builtin_amdgcn_s_setprio(1);
#pragma unroll
    for (int h = 0; h < 2; ++h) {
#pragma unroll
      for (int mt = 0; mt < 4; ++mt) {
        float pv0 = __builtin_amdgcn_exp2f(sT[h][mt][0] - mrun[h]);
        float pv1 = __builtin_amdgcn_exp2f(sT[h][mt][1] - mrun[h]);
        float pv2 = __builtin_amdgcn_exp2f(sT[h][mt][2] - mrun[h]);
        float pv3 = __builtin_amdgcn_exp2f(sT[h][mt][3] - mrun[h]);
        fp16x2 p01 = __builtin_amdgcn_cvt_pkrtz(pv0, pv1);
        fp16x2 p23 = __builtin_amdgcn_cvt_pkrtz(pv2, pv3);
        half4_t pf;
        pf[0] = (_Float16)p01[0]; pf[1] = (_Float16)p01[1];
        pf[2] = (_Float16)p23[0]; pf[3] = (_Float16)p23[1];
        accl[h] = __builtin_amdgcn_mfma_f32_16x16x16f16(ones4, pf, accl[h], 0, 0, 0);
#pragma unroll
        for (int dt = 0; dt < 4; ++dt)
          acc[h][dt] = __builtin_amdgcn_mfma_f32_16x16x16f16(vf[dt][mt], pf,
                                                             acc[h][dt], 0, 0, 0);
      }
    }
    __builtin_amdgcn_s_setprio(0);

    __syncthreads();
  }

#pragma unroll
  for (int h = 0; h < 2; ++h) {
    float linv = 1.f / accl[h][0];
#pragma unroll
    for (int mt = 0; mt < 4; ++mt)
#pragma unroll
      for (int r = 0; r < 4; ++r)
        Osh[(32 * w + 16 * h + c) * LDO + 16 * mt + 4 * g + r] = acc[h][mt][r] * linv;
  }
  __syncthreads();
  {
    int f8 = t & 7;
#pragma unroll
    for (int i = 0; i < 4; ++i) {
      int q = (t >> 3) + 32 * i;
#pragma unroll
      for (int j = 0; j < 2; ++j) {
        int c4 = f8 + 8 * j;
        f32x4 o = *(f32x4*)(Osh + q * LDO + c4 * 4);
        *(float4*)(Ob + (size_t)(qb + q) * D_DIM + c4 * 4) =
            make_float4(o.x, o.y, o.z, o.w);
      }
    }
  }
}

extern "C" void kernel_launch(void* const* d_in, const int* in_sizes, int n_in,
                              void* d_out, int out_size, void* d_ws, size_t ws_size,
                              hipStream_t stream) {
  (void)in_sizes; (void)n_in; (void)out_size;
  const float* Q = (const float*)d_in[0];
  const float* K = (const float*)d_in[1];
  const float* V = (const float*)d_in[2];
  const int*   M = (const int*)d_in[3];
  float* O = (float*)d_out;

  if (ws_size >= WS_NEED && d_ws != nullptr) {
    _Float16* wsK = (_Float16*)d_ws;
    _Float16* wsV = wsK + (size_t)32 * S_LEN * D_DIM;   // +8MB
    prep_kernel<<<dim3(2048), dim3(256), 0, stream>>>(K, V, wsK, wsV);
    fattn_dma<<<dim3(32 * 16), dim3(256), 0, stream>>>(Q, wsK, wsV, M, O);
  } else {
    fattn_fb<<<dim3(32 * 16), dim3(256), 0, stream>>>(Q, K, V, M, O);
  }
}